// Round 6
// baseline (303.967 us; speedup 1.0000x reference)
//
#include <hip/hip_runtime.h>

typedef __bf16 bf16;
typedef __attribute__((ext_vector_type(8))) __bf16 bf16x8;
typedef __attribute__((ext_vector_type(4))) __bf16 bf16x4;
typedef __attribute__((ext_vector_type(4))) float f32x4;

#define S_LEN 2048
#define DM 1024
#define NB 4

// ---- async 16B global -> LDS (global_load_lds_dwordx4) ----
__device__ __forceinline__ void async_copy16(const void* g, void* l)
{
    __builtin_amdgcn_global_load_lds(
        (const __attribute__((address_space(1))) unsigned int*)g,
        (__attribute__((address_space(3))) unsigned int*)l,
        16, 0, 0);
}

#define VM_WAIT8 asm volatile("s_waitcnt vmcnt(8)" ::: "memory")
#define VM_WAIT0 asm volatile("s_waitcnt vmcnt(0)" ::: "memory")
#define LGKM0    asm volatile("s_waitcnt lgkmcnt(0)" ::: "memory")
#define BAR      asm volatile("s_barrier" ::: "memory")

// =====================================================================
// 128x128 NT GEMM tile, BK=64, 4 waves (2x2), double-buffered LDS
// (2 x [A 16K | B 16K] = 64 KB -> 2 blocks/CU = 2 waves/SIMD).
// PROVEN core. Per-block K-step ~1.35us (2 blocks/CU overlapped ->
// 0.675us per CU-step). Phase makespan = longest RESIDENT block, not
// CU-sum -- drove the round-6 pv K-split.
// =====================================================================

__device__ __forceinline__ void stage_issue(const char* aGk, size_t aRow32,
                                            const char* bGk, size_t bRow32,
                                            char* aL, char* bL)
{
#pragma unroll
    for (int i = 0; i < 4; i++) {
        async_copy16(aGk + i * aRow32, aL + i * 4096);
        async_copy16(bGk + i * bRow32, bL + i * 4096);
    }
}

__device__ __forceinline__ void read_frags(const char* bufA, const char* bufB,
                                           int wr, int wc, int l16, int quad,
                                           bf16x8 (&af)[2][4], bf16x8 (&bfr)[2][4])
{
    const int swz = l16 & 7;
#pragma unroll
    for (int kk = 0; kk < 2; kk++) {
        const int col = (((kk << 2) + quad) ^ swz) << 4;
#pragma unroll
        for (int t = 0; t < 4; t++) {
            af[kk][t]  = *(const bf16x8*)(bufA + (wr * 64 + t * 16 + l16) * 128 + col);
            bfr[kk][t] = *(const bf16x8*)(bufB + (wc * 64 + t * 16 + l16) * 128 + col);
        }
    }
}

__device__ __forceinline__ void mfma_all(const bf16x8 (&af)[2][4],
                                         const bf16x8 (&bfr)[2][4],
                                         f32x4 (&acc)[4][4])
{
#pragma unroll
    for (int kk = 0; kk < 2; kk++)
#pragma unroll
        for (int rt = 0; rt < 4; rt++)
#pragma unroll
            for (int ct = 0; ct < 4; ct++)
                acc[rt][ct] = __builtin_amdgcn_mfma_f32_16x16x32_bf16(
                    af[kk][rt], bfr[kk][ct], acc[rt][ct], 0, 0, 0);
}

// A: 128 rows x K (row-major, lda elems); B: 128 rows x K (row-major, ldb).
// kSteps even, >=2. smem: 64 KB.
__device__ __forceinline__ void gemm_tile(
    const bf16* __restrict__ A, int lda,
    const bf16* __restrict__ B, int ldb,
    int kSteps, char* smem, f32x4 (&acc)[4][4])
{
    const int tid = threadIdx.x;
    const int w = tid >> 6, lane = tid & 63;
    const int quad = lane >> 4, l16 = lane & 15;
    const int wr = w >> 1, wc = w & 1;

#pragma unroll
    for (int i = 0; i < 4; i++)
#pragma unroll
        for (int j = 0; j < 4; j++) acc[i][j] = f32x4{0.f, 0.f, 0.f, 0.f};

    const int srow = tid >> 3;
    const int sc8  = tid & 7;
    const int srcCol = (sc8 ^ (srow & 7)) * 16;
    const char* aG = (const char*)(A + (size_t)srow * lda) + srcCol;
    const char* bG = (const char*)(B + (size_t)srow * ldb) + srcCol;
    const size_t aRow32 = (size_t)lda * 64;
    const size_t bRow32 = (size_t)ldb * 64;
    char* aL0 = smem +     0 + w * 1024;
    char* bL0 = smem + 16384 + w * 1024;
    char* aL1 = smem + 32768 + w * 1024;
    char* bL1 = smem + 49152 + w * 1024;

    stage_issue(aG,       aRow32, bG,       bRow32, aL0, bL0);   // tile 0 -> buf0
    stage_issue(aG + 128, aRow32, bG + 128, bRow32, aL1, bL1);   // tile 1 -> buf1

    for (int ks = 0; ks < kSteps; ks += 2) {
        const bool more = (ks + 2 < kSteps);
        bf16x8 af[2][4], bfr[2][4];

        // ---- phase A: consume buf0 (tile ks) ----
        VM_WAIT8;
        BAR;
        read_frags(smem, smem + 16384, wr, wc, l16, quad, af, bfr);
        LGKM0;
        BAR;
        if (more)
            stage_issue(aG + (size_t)(ks + 2) * 128, aRow32,
                        bG + (size_t)(ks + 2) * 128, bRow32, aL0, bL0);
        mfma_all(af, bfr, acc);

        // ---- phase B: consume buf1 (tile ks+1) ----
        if (more) { VM_WAIT8; } else { VM_WAIT0; }
        BAR;
        read_frags(smem + 32768, smem + 49152, wr, wc, l16, quad, af, bfr);
        LGKM0;
        BAR;
        if (more)
            stage_issue(aG + (size_t)(ks + 3) * 128, aRow32,
                        bG + (size_t)(ks + 3) * 128, bRow32, aL1, bL1);
        mfma_all(af, bfr, acc);
    }
}

// ---- PREP: lsum zero + Out zero (atomic regions) + fp32->bf16 casts.
// bid 0: lsum; 1..2048: Out zero (rows>=1024 per batch always; all rows
// when non-causal -- pv K-split chunks atomicAdd there); 2049..3584: W;
// 3585..15872: Eq,Ek,Ev. All BW-bound, one launch. ----
__global__ __launch_bounds__(256) void prep_kernel(
    const float* __restrict__ Wq, const float* __restrict__ Wk, const float* __restrict__ Wv,
    const float* __restrict__ Eq, const float* __restrict__ Ek, const float* __restrict__ Ev,
    bf16* __restrict__ Wqb, bf16* __restrict__ Wkb, bf16* __restrict__ Wvb,
    bf16* __restrict__ Eqb, bf16* __restrict__ Ekb, bf16* __restrict__ Evb,
    float* __restrict__ lsum, float* __restrict__ Out, const int* __restrict__ maskp)
{
    const int bid = blockIdx.x;
    const int tid = threadIdx.x;
    if (bid == 0) {
        for (int j = tid; j < NB * S_LEN; j += 256) lsum[j] = 0.0f;
        return;
    }
    if (bid <= 2048) {
        // Out zero: 16 KB per block = 4 rows (4 KB/row); blocks never
        // straddle the row-1024 boundary (4 | 1024).
        const int z = bid - 1;
        const size_t o = (size_t)z * 16384;            // byte offset in Out
        const int rowInBatch = (int)((o >> 12) & (S_LEN - 1));
        const bool causal = (maskp[0] != 0);
        if (causal && rowInBatch < 1024) return;       // plain-store region
        f32x4* p = (f32x4*)((char*)Out + o);
        const f32x4 zv = {0.f, 0.f, 0.f, 0.f};
#pragma unroll
        for (int i = 0; i < 4; i++) p[tid + 256 * i] = zv;
        return;
    }
    const float* src;
    bf16* dst;
    size_t i;
    if (bid <= 3584) {
        const int q = bid - 2049;            // 0..1535
        const int z = q >> 9;                // 0..2
        src = z == 0 ? Wq : z == 1 ? Wk : Wv;
        dst = z == 0 ? Wqb : z == 1 ? Wkb : Wvb;
        i = ((size_t)(q & 511) * 256 + tid) * 8;
    } else {
        const int q = bid - 3585;            // 0..12287
        const int z = q >> 12;               // 0..2
        src = z == 0 ? Eq : z == 1 ? Ek : Ev;
        dst = z == 0 ? Eqb : z == 1 ? Ekb : Evb;
        i = ((size_t)(q & 4095) * 256 + tid) * 8;
    }
    f32x4 a = *(const f32x4*)(src + i);
    f32x4 b = *(const f32x4*)(src + i + 4);
    bf16x8 o;
    o[0] = (bf16)a[0]; o[1] = (bf16)a[1]; o[2] = (bf16)a[2]; o[3] = (bf16)a[3];
    o[4] = (bf16)b[0]; o[5] = (bf16)b[1]; o[6] = (bf16)b[2]; o[7] = (bf16)b[3];
    *(bf16x8*)(dst + i) = o;
}

// ---- projection Q,K: O = E @ W^T + b. Grid 1024 pure (= exactly 2 full
// rounds at 2 blocks/CU). ROUND-6: Ev-cvt backfill REVERTED (it added
// ~18us to this kernel for ~8us prep savings, round-5 measured). ----
__global__ __launch_bounds__(256) void projqk_kernel(
    const bf16* __restrict__ Eq, const bf16* __restrict__ Ek,
    const bf16* __restrict__ Wq, const bf16* __restrict__ Wk,
    const float* __restrict__ bq, const float* __restrict__ bk,
    bf16* __restrict__ Qo, bf16* __restrict__ Ko)
{
    __shared__ __align__(16) char smem[65536];
    const int bid = blockIdx.x;
    const int c = bid & 7;
    const int j = bid >> 3;          // 0..127
    const int z = j >> 6;            // 0..1
    const int r64 = j & 63;
    const int m0 = (c * 8 + (r64 >> 3)) * 128;
    const int n0 = (r64 & 7) * 128;

    const bf16* E     = z == 0 ? Eq : Ek;
    const bf16* W     = z == 0 ? Wq : Wk;
    const float* bias = z == 0 ? bq : bk;

    f32x4 acc[4][4];
    gemm_tile(E + (size_t)m0 * DM, DM, W + (size_t)n0 * DM, DM, DM / 64, smem, acc);

    const int tid = threadIdx.x;
    const int w = tid >> 6, lane = tid & 63;
    const int quad = lane >> 4, l16 = lane & 15;
    const int wr = w >> 1, wc = w & 1;
    const int nBase = n0 + wc * 64;

    float bcol[4];
#pragma unroll
    for (int ct = 0; ct < 4; ct++) bcol[ct] = bias[nBase + ct * 16 + l16];

    __syncthreads();   // smem reuse (no DMA outstanding after VM_WAIT0)
    bf16* Tt = (bf16*)smem;   // 128 x 136 (rows 16B-aligned)
#pragma unroll
    for (int rt = 0; rt < 4; rt++)
#pragma unroll
        for (int ct = 0; ct < 4; ct++)
#pragma unroll
            for (int r = 0; r < 4; r++)
                Tt[(wr * 64 + rt * 16 + quad * 4 + r) * 136 + wc * 64 + ct * 16 + l16]
                    = (bf16)(acc[rt][ct][r] + bcol[ct]);
    __syncthreads();
    bf16* O = z == 0 ? Qo : Ko;
    const int row = tid >> 1, half = tid & 1;
    const bf16* src = Tt + row * 136 + half * 64;
    bf16* dst = O + (size_t)(m0 + row) * DM + n0 + half * 64;
#pragma unroll
    for (int i = 0; i < 8; i++)
        *(bf16x8*)(dst + i * 8) = *(const bf16x8*)(src + i * 8);
}

// ---- MERGED: projV (blocks 0..511) + QK^T/exp (blocks 512..1535).
// qk's dead causal blocks retire instantly; projV backfills slots.
// Memory-safe: qk writes P (overlays Eqb/Ekb staging only); projV reads Evb
// (disjoint overlay region) and writes Vtb. (Round-3 structure, kept.) ----
__global__ __launch_bounds__(256) void projv_qk_kernel(
    const bf16* __restrict__ Ev, const bf16* __restrict__ Wv,
    const float* __restrict__ bv, bf16* __restrict__ Vt,
    const bf16* __restrict__ Q, const bf16* __restrict__ K,
    const int* __restrict__ maskp, bf16* __restrict__ P, float* __restrict__ lsum)
{
    __shared__ __align__(16) char smem[65536];
    const int bid = blockIdx.x;
    const int tid = threadIdx.x;
    const int w = tid >> 6, lane = tid & 63;
    const int quad = lane >> 4, l16 = lane & 15;
    const int wr = w >> 1, wc = w & 1;

    if (bid < 512) {
        // ================= projV: Vt[b][d][s] = (Ev @ Wv^T + bv)^T ======
        const int c = bid & 7;
        const int r64 = bid >> 3;        // 0..63
        const int m0 = (c * 8 + (r64 >> 3)) * 128;
        const int n0 = (r64 & 7) * 128;

        f32x4 acc[4][4];
        gemm_tile(Ev + (size_t)m0 * DM, DM, Wv + (size_t)n0 * DM, DM, DM / 64, smem, acc);

        const int nBase = n0 + wc * 64;
        float bcol[4];
#pragma unroll
        for (int ct = 0; ct < 4; ct++) bcol[ct] = bv[nBase + ct * 16 + l16];

        // Vt[b][d][s]: lane holds 4 consecutive s for fixed d -> 8B store
        const int mBase = m0 + wr * 64;
#pragma unroll
        for (int rt = 0; rt < 4; rt++) {
            const int m = mBase + rt * 16 + quad * 4;
            const int bb = m >> 11;
            const int s  = m & 2047;
#pragma unroll
            for (int ct = 0; ct < 4; ct++) {
                const int n = nBase + ct * 16 + l16;
                bf16x4 o;
                o[0] = (bf16)(acc[rt][ct][0] + bcol[ct]);
                o[1] = (bf16)(acc[rt][ct][1] + bcol[ct]);
                o[2] = (bf16)(acc[rt][ct][2] + bcol[ct]);
                o[3] = (bf16)(acc[rt][ct][3] + bcol[ct]);
                *(bf16x4*)(Vt + ((size_t)(bb * DM + n)) * S_LEN + s) = o;
            }
        }
    } else {
        // ================= qk: P = exp(Q K^T / 32), row sums =============
        const int qbid = bid - 512;          // 0..1023
        const int c = qbid & 7;
        const int j = qbid >> 3;             // 0..127
        const int b = j >> 5;
        const int jj = j & 31;
        const int kt = (jj < 16) ? c : (15 - c);
        const int qt = jj & 15;
        const bool causal = (maskp[0] != 0);
        if (causal && kt > qt) return;

        f32x4 acc[4][4];
        const bf16* Qb = Q + ((size_t)(b * S_LEN + qt * 128)) * DM;
        const bf16* Kb = K + ((size_t)(b * S_LEN + kt * 128)) * DM;
        gemm_tile(Qb, DM, Kb, DM, DM / 64, smem, acc);

        const float scale = 0.03125f;  // 1/sqrt(1024)

        __syncthreads();
        bf16* Pt = (bf16*)smem;   // 128 x 136
#pragma unroll
        for (int rt = 0; rt < 4; rt++)
#pragma unroll
            for (int r = 0; r < 4; r++) {
                const int rloc = wr * 64 + rt * 16 + quad * 4 + r;
                const int qg = qt * 128 + rloc;
#pragma unroll
                for (int ct = 0; ct < 4; ct++) {
                    const int kg = kt * 128 + wc * 64 + ct * 16 + l16;
                    float p = (!causal || kg <= qg) ? __expf(acc[rt][ct][r] * scale) : 0.0f;
                    Pt[rloc * 136 + wc * 64 + ct * 16 + l16] = (bf16)p;
                }
            }
        __syncthreads();

        bf16* Pb = P + (size_t)b * S_LEN * S_LEN;
        float* lb = lsum + b * S_LEN;
        const int row = tid >> 1, half = tid & 1;
        const bf16* src = Pt + row * 136 + half * 64;
        bf16* dst = Pb + (size_t)(qt * 128 + row) * S_LEN + kt * 128 + half * 64;
        float rs = 0.0f;
#pragma unroll
        for (int i = 0; i < 8; i++) {
            bf16x8 x = *(const bf16x8*)(src + i * 8);
            *(bf16x8*)(dst + i * 8) = x;
#pragma unroll
            for (int e = 0; e < 8; e++) rs += (float)x[e];   // sum rounded values PV uses
        }
        rs += __shfl_xor(rs, 1);
        if (half == 0) atomicAdd(&lb[qt * 128 + row], rs);
    }
}

// ---- O = (P @ Vt^T) / l. ROUND-6: K-SPLIT. Phase makespan = LONGEST
// resident block (2/CU, all resident t=0), so qt=15's 32-step chain
// (~43us) was the floor regardless of pairing tables (rounds 3-5).
// Every tile with kTotal>16 steps splits into two chunks (each <=16 even
// steps); both chunks atomicAdd acc*inv (linear in P-rows, so partials
// sum exactly); their Out rows are pre-zeroed in prep. Causal qt<8 stays
// single-writer plain-store (rows<1024 not zeroed). Grid 1024: bids
// 0..511 = heavy (causal qt>=8 / all when non-causal region A) dispatch
// first; 512..1023 = light (qt<8; ch1 dead when causal -> backfill).
// XCD c=bid&7 owns (b=c>>1, par=c&1): P-panels (4x512K) L2-local. ----
__global__ __launch_bounds__(256) void pv_kernel(
    const bf16* __restrict__ P, const bf16* __restrict__ Vt,
    const float* __restrict__ lsum, const int* __restrict__ maskp,
    float* __restrict__ Out)
{
    const int bid = blockIdx.x;          // 0..1023
    const bool heavy = bid < 512;
    const int v = heavy ? bid : bid - 512;
    const int c = v & 7;                 // XCD
    const int b = c >> 1;
    const int par = c & 1;
    const int u = v >> 3;                // 0..63
    const int dt = u & 7;
    const int ch = (u >> 5) & 1;
    const int qti = 3 - ((u >> 3) & 3);  // descending: longest first
    const int qt = heavy ? (8 + qti * 2 + par) : (qti * 2 + par);
    const bool causal = (maskp[0] != 0);
    const int kTotal = causal ? (qt + 1) * 2 : (S_LEN / 64);

    const bool whole = causal && !heavy;     // qt<8 causal: single chunk
    int sBeg, sCnt;
    if (whole) {
        if (ch == 1) return;                 // dead; instant backfill
        sBeg = 0; sCnt = kTotal;
    } else {
        const int s0 = ((kTotal / 2) + 1) & ~1;   // even, >= half, <=16
        if (ch == 0) { sBeg = 0;  sCnt = s0; }
        else         { sBeg = s0; sCnt = kTotal - s0; if (sCnt <= 0) return; }
    }

    __shared__ __align__(16) char smem[65536];

    f32x4 acc[4][4];
    const bf16* Pb = P + ((size_t)b * S_LEN + qt * 128) * S_LEN + (size_t)sBeg * 64;
    const bf16* Vb = Vt + ((size_t)(b * DM + dt * 128)) * S_LEN + (size_t)sBeg * 64;
    gemm_tile(Pb, S_LEN, Vb, S_LEN, sCnt, smem, acc);

    const int tid = threadIdx.x;
    const int w = tid >> 6, lane = tid & 63;
    const int quad = lane >> 4, l16 = lane & 15;
    const int wr = w >> 1, wc = w & 1;

    const float* lb = lsum + b * S_LEN;
    float inv[4][4];
#pragma unroll
    for (int rt = 0; rt < 4; rt++)
#pragma unroll
        for (int r = 0; r < 4; r++)
            inv[rt][r] = 1.0f / lb[qt * 128 + wr * 64 + rt * 16 + quad * 4 + r];

    if (whole) {
        // single-writer: coalesced f32x4 stores via LDS transpose
        __syncthreads();
        float* Ot = (float*)smem;   // 64 x 132 (rows 16B-aligned)
#pragma unroll
        for (int h = 0; h < 2; h++) {
            if (wr == h) {
#pragma unroll
                for (int rt = 0; rt < 4; rt++)
#pragma unroll
                    for (int r = 0; r < 4; r++) {
                        const int rloc = rt * 16 + quad * 4 + r;
#pragma unroll
                        for (int ct = 0; ct < 4; ct++)
                            Ot[rloc * 132 + wc * 64 + ct * 16 + l16] = acc[rt][ct][r] * inv[rt][r];
                    }
            }
            __syncthreads();
            const int row = tid >> 2, qq = tid & 3;
            const float* src = Ot + row * 132 + qq * 32;
            float* dst = Out + (size_t)(b * S_LEN + qt * 128 + h * 64 + row) * DM + dt * 128 + qq * 32;
#pragma unroll
            for (int i = 0; i < 8; i++)
                *(f32x4*)(dst + i * 4) = *(const f32x4*)(src + i * 4);
            __syncthreads();
        }
    } else {
        // multi-writer chunk: atomicAdd pre-normalized partials (16 lanes
        // x 4B consecutive per row-segment -> cacheline-grouped)
        const int rowBase = b * S_LEN + qt * 128 + wr * 64;
        const int colBase = dt * 128 + wc * 64;
#pragma unroll
        for (int rt = 0; rt < 4; rt++)
#pragma unroll
            for (int r = 0; r < 4; r++) {
                float* rp = Out + (size_t)(rowBase + rt * 16 + quad * 4 + r) * DM + colBase;
                const float s = inv[rt][r];
#pragma unroll
                for (int ct = 0; ct < 4; ct++)
                    atomicAdd(rp + ct * 16 + l16, acc[rt][ct][r] * s);
            }
    }
}

extern "C" void kernel_launch(void* const* d_in, const int* in_sizes, int n_in,
                              void* d_out, int out_size, void* d_ws, size_t ws_size,
                              hipStream_t stream)
{
    const float* Eq = (const float*)d_in[0];
    const float* Ek = (const float*)d_in[1];
    const float* Ev = (const float*)d_in[2];
    const float* Wq = (const float*)d_in[3];
    const float* bq = (const float*)d_in[4];
    const float* Wk = (const float*)d_in[5];
    const float* bk = (const float*)d_in[6];
    const float* Wv = (const float*)d_in[7];
    const float* bv = (const float*)d_in[8];
    const int* maskp = (const int*)d_in[9];
    float* Out = (float*)d_out;

    // ws layout (~103 MB):
    //  [Qb 16M][Kb 16M][Vtb 16M][Wqb 2M][Wkb 2M][Wvb 2M][lsum 1M][P 32M | Eb overlay 48M]
    char* ws = (char*)d_ws;
    const size_t SZ_QKV = (size_t)NB * S_LEN * DM * 2;
    const size_t SZ_W   = (size_t)DM * DM * 2;
    bf16* Qb  = (bf16*)(ws);
    bf16* Kb  = (bf16*)(ws + SZ_QKV);
    bf16* Vtb = (bf16*)(ws + 2 * SZ_QKV);
    bf16* Wqb = (bf16*)(ws + 3 * SZ_QKV);
    bf16* Wkb = (bf16*)(ws + 3 * SZ_QKV + SZ_W);
    bf16* Wvb = (bf16*)(ws + 3 * SZ_QKV + 2 * SZ_W);
    float* lsum = (float*)(ws + 3 * SZ_QKV + 3 * SZ_W);
    bf16* Pbuf = (bf16*)(ws + 3 * SZ_QKV + 3 * SZ_W + (1 << 20));
    bf16* Eqb = Pbuf;   // E bf16 staging overlays P (dead once proj completes)
    bf16* Ekb = Eqb + (size_t)NB * S_LEN * DM;
    bf16* Evb = Ekb + (size_t)NB * S_LEN * DM;

    prep_kernel<<<15873, 256, 0, stream>>>(
        Wq, Wk, Wv, Eq, Ek, Ev, Wqb, Wkb, Wvb, Eqb, Ekb, Evb, lsum, Out, maskp);

    projqk_kernel<<<1024, 256, 0, stream>>>(
        Eqb, Ekb, Wqb, Wkb, bq, bk, Qb, Kb);

    projv_qk_kernel<<<1536, 256, 0, stream>>>(
        Evb, Wvb, bv, Vtb, Qb, Kb, maskp, Pbuf, lsum);

    pv_kernel<<<1024, 256, 0, stream>>>(Pbuf, Vtb, lsum, maskp, Out);
}

// Round 7
// 284.614 us; speedup vs baseline: 1.0680x; 1.0680x over previous
//
#include <hip/hip_runtime.h>

typedef __bf16 bf16;
typedef __attribute__((ext_vector_type(8))) __bf16 bf16x8;
typedef __attribute__((ext_vector_type(4))) __bf16 bf16x4;
typedef __attribute__((ext_vector_type(4))) float f32x4;

#define S_LEN 2048
#define DM 1024
#define NB 4

// ---- async 16B global -> LDS (global_load_lds_dwordx4) ----
__device__ __forceinline__ void async_copy16(const void* g, void* l)
{
    __builtin_amdgcn_global_load_lds(
        (const __attribute__((address_space(1))) unsigned int*)g,
        (__attribute__((address_space(3))) unsigned int*)l,
        16, 0, 0);
}

#define VM_WAIT8 asm volatile("s_waitcnt vmcnt(8)" ::: "memory")
#define VM_WAIT0 asm volatile("s_waitcnt vmcnt(0)" ::: "memory")
#define LGKM0    asm volatile("s_waitcnt lgkmcnt(0)" ::: "memory")
#define BAR      asm volatile("s_barrier" ::: "memory")

// =====================================================================
// 128x128 NT GEMM tile, BK=64, 4 waves (2x2), double-buffered LDS
// (2 x [A 16K | B 16K] = 64 KB -> 2 blocks/CU = 2 waves/SIMD).
// PROVEN core (~795 TF effective). Round-6 lesson: longest-resident-block
// bounds each phase; atomic K-split poisons neighboring dispatches
// (projv_qk 57->80us with LOWER BW) -- plain stores only.
// =====================================================================

__device__ __forceinline__ void stage_issue(const char* aGk, size_t aRow32,
                                            const char* bGk, size_t bRow32,
                                            char* aL, char* bL)
{
#pragma unroll
    for (int i = 0; i < 4; i++) {
        async_copy16(aGk + i * aRow32, aL + i * 4096);
        async_copy16(bGk + i * bRow32, bL + i * 4096);
    }
}

__device__ __forceinline__ void read_frags(const char* bufA, const char* bufB,
                                           int wr, int wc, int l16, int quad,
                                           bf16x8 (&af)[2][4], bf16x8 (&bfr)[2][4])
{
    const int swz = l16 & 7;
#pragma unroll
    for (int kk = 0; kk < 2; kk++) {
        const int col = (((kk << 2) + quad) ^ swz) << 4;
#pragma unroll
        for (int t = 0; t < 4; t++) {
            af[kk][t]  = *(const bf16x8*)(bufA + (wr * 64 + t * 16 + l16) * 128 + col);
            bfr[kk][t] = *(const bf16x8*)(bufB + (wc * 64 + t * 16 + l16) * 128 + col);
        }
    }
}

__device__ __forceinline__ void mfma_all(const bf16x8 (&af)[2][4],
                                         const bf16x8 (&bfr)[2][4],
                                         f32x4 (&acc)[4][4])
{
#pragma unroll
    for (int kk = 0; kk < 2; kk++)
#pragma unroll
        for (int rt = 0; rt < 4; rt++)
#pragma unroll
            for (int ct = 0; ct < 4; ct++)
                acc[rt][ct] = __builtin_amdgcn_mfma_f32_16x16x32_bf16(
                    af[kk][rt], bfr[kk][ct], acc[rt][ct], 0, 0, 0);
}

// A: 128 rows x K (row-major, lda elems); B: 128 rows x K (row-major, ldb).
// kSteps even, >=2. smem: 64 KB.
__device__ __forceinline__ void gemm_tile(
    const bf16* __restrict__ A, int lda,
    const bf16* __restrict__ B, int ldb,
    int kSteps, char* smem, f32x4 (&acc)[4][4])
{
    const int tid = threadIdx.x;
    const int w = tid >> 6, lane = tid & 63;
    const int quad = lane >> 4, l16 = lane & 15;
    const int wr = w >> 1, wc = w & 1;

#pragma unroll
    for (int i = 0; i < 4; i++)
#pragma unroll
        for (int j = 0; j < 4; j++) acc[i][j] = f32x4{0.f, 0.f, 0.f, 0.f};

    const int srow = tid >> 3;
    const int sc8  = tid & 7;
    const int srcCol = (sc8 ^ (srow & 7)) * 16;
    const char* aG = (const char*)(A + (size_t)srow * lda) + srcCol;
    const char* bG = (const char*)(B + (size_t)srow * ldb) + srcCol;
    const size_t aRow32 = (size_t)lda * 64;
    const size_t bRow32 = (size_t)ldb * 64;
    char* aL0 = smem +     0 + w * 1024;
    char* bL0 = smem + 16384 + w * 1024;
    char* aL1 = smem + 32768 + w * 1024;
    char* bL1 = smem + 49152 + w * 1024;

    stage_issue(aG,       aRow32, bG,       bRow32, aL0, bL0);   // tile 0 -> buf0
    stage_issue(aG + 128, aRow32, bG + 128, bRow32, aL1, bL1);   // tile 1 -> buf1

    for (int ks = 0; ks < kSteps; ks += 2) {
        const bool more = (ks + 2 < kSteps);
        bf16x8 af[2][4], bfr[2][4];

        // ---- phase A: consume buf0 (tile ks) ----
        VM_WAIT8;        // own tile-ks loads landed (tile ks+1 still in flight)
        BAR;             // all threads' tile-ks loads landed
        read_frags(smem, smem + 16384, wr, wc, l16, quad, af, bfr);
        LGKM0;           // frag data in registers
        BAR;             // all waves done reading buf0 -> safe to overwrite
        if (more)
            stage_issue(aG + (size_t)(ks + 2) * 128, aRow32,
                        bG + (size_t)(ks + 2) * 128, bRow32, aL0, bL0);
        mfma_all(af, bfr, acc);

        // ---- phase B: consume buf1 (tile ks+1) ----
        if (more) { VM_WAIT8; } else { VM_WAIT0; }
        BAR;
        read_frags(smem + 32768, smem + 49152, wr, wc, l16, quad, af, bfr);
        LGKM0;
        BAR;
        if (more)
            stage_issue(aG + (size_t)(ks + 3) * 128, aRow32,
                        bG + (size_t)(ks + 3) * 128, bRow32, aL1, bL1);
        mfma_all(af, bfr, acc);
    }
}

// ---- PREP: fp32->bf16 casts for W (3x1M) and E (3x8M) + lsum zero,
// fused into one launch (round-4 form, measured neutral vs split; no
// Out-zero, no atomics downstream). bid 0: lsum; 1..1536: W;
// 1537..13824: E. ----
__global__ __launch_bounds__(256) void prep_kernel(
    const float* __restrict__ Wq, const float* __restrict__ Wk, const float* __restrict__ Wv,
    const float* __restrict__ Eq, const float* __restrict__ Ek, const float* __restrict__ Ev,
    bf16* __restrict__ Wqb, bf16* __restrict__ Wkb, bf16* __restrict__ Wvb,
    bf16* __restrict__ Eqb, bf16* __restrict__ Ekb, bf16* __restrict__ Evb,
    float* __restrict__ lsum)
{
    const int bid = blockIdx.x;
    const int tid = threadIdx.x;
    if (bid == 0) {
        for (int j = tid; j < NB * S_LEN; j += 256) lsum[j] = 0.0f;
        return;
    }
    const float* src;
    bf16* dst;
    size_t i;
    if (bid <= 1536) {
        const int q = bid - 1;               // 0..1535
        const int z = q >> 9;                // 0..2
        src = z == 0 ? Wq : z == 1 ? Wk : Wv;
        dst = z == 0 ? Wqb : z == 1 ? Wkb : Wvb;
        i = ((size_t)(q & 511) * 256 + tid) * 8;
    } else {
        const int q = bid - 1537;            // 0..12287
        const int z = q >> 12;               // 0..2
        src = z == 0 ? Eq : z == 1 ? Ek : Ev;
        dst = z == 0 ? Eqb : z == 1 ? Ekb : Evb;
        i = ((size_t)(q & 4095) * 256 + tid) * 8;
    }
    f32x4 a = *(const f32x4*)(src + i);
    f32x4 b = *(const f32x4*)(src + i + 4);
    bf16x8 o;
    o[0] = (bf16)a[0]; o[1] = (bf16)a[1]; o[2] = (bf16)a[2]; o[3] = (bf16)a[3];
    o[4] = (bf16)b[0]; o[5] = (bf16)b[1]; o[6] = (bf16)b[2]; o[7] = (bf16)b[3];
    *(bf16x8*)(dst + i) = o;
}

// ---- projection Q,K: O = E @ W^T + b. Grid 1024 pure (= exactly 2 full
// rounds at 2 blocks/CU; round-5 proved cvt backfill here costs +18us). ----
__global__ __launch_bounds__(256) void projqk_kernel(
    const bf16* __restrict__ Eq, const bf16* __restrict__ Ek,
    const bf16* __restrict__ Wq, const bf16* __restrict__ Wk,
    const float* __restrict__ bq, const float* __restrict__ bk,
    bf16* __restrict__ Qo, bf16* __restrict__ Ko)
{
    __shared__ __align__(16) char smem[65536];
    const int bid = blockIdx.x;
    const int c = bid & 7;
    const int j = bid >> 3;          // 0..127
    const int z = j >> 6;            // 0..1
    const int r64 = j & 63;
    const int m0 = (c * 8 + (r64 >> 3)) * 128;
    const int n0 = (r64 & 7) * 128;

    const bf16* E     = z == 0 ? Eq : Ek;
    const bf16* W     = z == 0 ? Wq : Wk;
    const float* bias = z == 0 ? bq : bk;

    f32x4 acc[4][4];
    gemm_tile(E + (size_t)m0 * DM, DM, W + (size_t)n0 * DM, DM, DM / 64, smem, acc);

    const int tid = threadIdx.x;
    const int w = tid >> 6, lane = tid & 63;
    const int quad = lane >> 4, l16 = lane & 15;
    const int wr = w >> 1, wc = w & 1;
    const int nBase = n0 + wc * 64;

    float bcol[4];
#pragma unroll
    for (int ct = 0; ct < 4; ct++) bcol[ct] = bias[nBase + ct * 16 + l16];

    __syncthreads();   // smem reuse (no DMA outstanding after VM_WAIT0)
    bf16* Tt = (bf16*)smem;   // 128 x 136 (rows 16B-aligned)
#pragma unroll
    for (int rt = 0; rt < 4; rt++)
#pragma unroll
        for (int ct = 0; ct < 4; ct++)
#pragma unroll
            for (int r = 0; r < 4; r++)
                Tt[(wr * 64 + rt * 16 + quad * 4 + r) * 136 + wc * 64 + ct * 16 + l16]
                    = (bf16)(acc[rt][ct][r] + bcol[ct]);
    __syncthreads();
    bf16* O = z == 0 ? Qo : Ko;
    const int row = tid >> 1, half = tid & 1;
    const bf16* src = Tt + row * 136 + half * 64;
    bf16* dst = O + (size_t)(m0 + row) * DM + n0 + half * 64;
#pragma unroll
    for (int i = 0; i < 8; i++)
        *(bf16x8*)(dst + i * 8) = *(const bf16x8*)(src + i * 8);
}

// ---- MERGED: QK^T/exp (blocks 0..1023) + projV (blocks 1024..1535).
// ROUND-7 ORDER SWAP: qk FIRST so its ~480 dead causal blocks retire in
// the first dispatch wave and its heavy-epilogue actives start earliest;
// the uniform 16-step projV tiles are the ideal backfill filler (makespan
// = last-STARTED real work; previously that was a heavy qk tile).
// Memory-safe: qk writes P (overlays Eqb/Ekb staging only); projV reads
// Evb (disjoint overlay region) and writes Vtb. ----
__global__ __launch_bounds__(256) void projv_qk_kernel(
    const bf16* __restrict__ Ev, const bf16* __restrict__ Wv,
    const float* __restrict__ bv, bf16* __restrict__ Vt,
    const bf16* __restrict__ Q, const bf16* __restrict__ K,
    const int* __restrict__ maskp, bf16* __restrict__ P, float* __restrict__ lsum)
{
    __shared__ __align__(16) char smem[65536];
    const int bid = blockIdx.x;
    const int tid = threadIdx.x;
    const int w = tid >> 6, lane = tid & 63;
    const int quad = lane >> 4, l16 = lane & 15;
    const int wr = w >> 1, wc = w & 1;

    if (bid < 1024) {
        // ================= qk: P = exp(Q K^T / 32), row sums =============
        const int qbid = bid;                // 0..1023
        const int c = qbid & 7;
        const int j = qbid >> 3;             // 0..127
        const int b = j >> 5;
        const int jj = j & 31;
        const int kt = (jj < 16) ? c : (15 - c);
        const int qt = jj & 15;
        const bool causal = (maskp[0] != 0);
        if (causal && kt > qt) return;

        f32x4 acc[4][4];
        const bf16* Qb = Q + ((size_t)(b * S_LEN + qt * 128)) * DM;
        const bf16* Kb = K + ((size_t)(b * S_LEN + kt * 128)) * DM;
        gemm_tile(Qb, DM, Kb, DM, DM / 64, smem, acc);

        const float scale = 0.03125f;  // 1/sqrt(1024)

        __syncthreads();
        bf16* Pt = (bf16*)smem;   // 128 x 136
#pragma unroll
        for (int rt = 0; rt < 4; rt++)
#pragma unroll
            for (int r = 0; r < 4; r++) {
                const int rloc = wr * 64 + rt * 16 + quad * 4 + r;
                const int qg = qt * 128 + rloc;
#pragma unroll
                for (int ct = 0; ct < 4; ct++) {
                    const int kg = kt * 128 + wc * 64 + ct * 16 + l16;
                    float p = (!causal || kg <= qg) ? __expf(acc[rt][ct][r] * scale) : 0.0f;
                    Pt[rloc * 136 + wc * 64 + ct * 16 + l16] = (bf16)p;
                }
            }
        __syncthreads();

        bf16* Pb = P + (size_t)b * S_LEN * S_LEN;
        float* lb = lsum + b * S_LEN;
        const int row = tid >> 1, half = tid & 1;
        const bf16* src = Pt + row * 136 + half * 64;
        bf16* dst = Pb + (size_t)(qt * 128 + row) * S_LEN + kt * 128 + half * 64;
        float rs = 0.0f;
#pragma unroll
        for (int i = 0; i < 8; i++) {
            bf16x8 x = *(const bf16x8*)(src + i * 8);
            *(bf16x8*)(dst + i * 8) = x;
#pragma unroll
            for (int e = 0; e < 8; e++) rs += (float)x[e];   // sum rounded values PV uses
        }
        rs += __shfl_xor(rs, 1);
        if (half == 0) atomicAdd(&lb[qt * 128 + row], rs);
    } else {
        // ================= projV: Vt[b][d][s] = (Ev @ Wv^T + bv)^T ======
        const int vbid = bid - 1024;     // 0..511
        const int c = vbid & 7;
        const int r64 = vbid >> 3;       // 0..63
        const int m0 = (c * 8 + (r64 >> 3)) * 128;
        const int n0 = (r64 & 7) * 128;

        f32x4 acc[4][4];
        gemm_tile(Ev + (size_t)m0 * DM, DM, Wv + (size_t)n0 * DM, DM, DM / 64, smem, acc);

        const int nBase = n0 + wc * 64;
        float bcol[4];
#pragma unroll
        for (int ct = 0; ct < 4; ct++) bcol[ct] = bv[nBase + ct * 16 + l16];

        // Vt[b][d][s]: lane holds 4 consecutive s for fixed d -> 8B store
        const int mBase = m0 + wr * 64;
#pragma unroll
        for (int rt = 0; rt < 4; rt++) {
            const int m = mBase + rt * 16 + quad * 4;
            const int bb = m >> 11;
            const int s  = m & 2047;
#pragma unroll
            for (int ct = 0; ct < 4; ct++) {
                const int n = nBase + ct * 16 + l16;
                bf16x4 o;
                o[0] = (bf16)(acc[rt][ct][0] + bcol[ct]);
                o[1] = (bf16)(acc[rt][ct][1] + bcol[ct]);
                o[2] = (bf16)(acc[rt][ct][2] + bcol[ct]);
                o[3] = (bf16)(acc[rt][ct][3] + bcol[ct]);
                *(bf16x4*)(Vt + ((size_t)(bb * DM + n)) * S_LEN + s) = o;
            }
        }
    }
}

// ---- O = (P @ Vt^T) / l. 512 blocks (2/CU). ROUND-5 TABLE (best pv
// measured): stride-32 CU pairing confirmed by round-4's +8.6us
// regression; complementary-at-distance-4 tables make kk and kk+4 sum to
// 15 -> every CU-pair totals 34 K-steps. par0 {15,12,11,8,0,3,4,7} =
// 0x74308BCF; par1 {14,13,10,9,1,2,5,6} = 0x65219ADE. XCD c owns
// (b=c>>1, par=c&1): P-panels + Vt[b] L2-local. Plain stores only. ----
__global__ __launch_bounds__(256) void pv_kernel(
    const bf16* __restrict__ P, const bf16* __restrict__ Vt,
    const float* __restrict__ lsum, const int* __restrict__ maskp,
    float* __restrict__ Out)
{
    const int bid = blockIdx.x;          // 0..511
    const int c = bid & 7;               // XCD
    const int b = c >> 1;
    const int par = c & 1;
    const int idx = bid >> 3;            // 0..63
    const int dt = idx & 7;
    const int qi = idx >> 3;             // 0..7
    const int kk = (qi + dt) & 7;
    const unsigned tbl = par ? 0x65219ADEu : 0x74308BCFu;
    const int qt = (tbl >> (kk * 4)) & 15;
    const bool causal = (maskp[0] != 0);
    const int kSteps = causal ? (qt + 1) * 2 : (S_LEN / 64);

    __shared__ __align__(16) char smem[65536];

    f32x4 acc[4][4];
    const bf16* Pb = P + ((size_t)b * S_LEN + qt * 128) * S_LEN;
    const bf16* Vb = Vt + ((size_t)(b * DM + dt * 128)) * S_LEN;
    gemm_tile(Pb, S_LEN, Vb, S_LEN, kSteps, smem, acc);

    const int tid = threadIdx.x;
    const int w = tid >> 6, lane = tid & 63;
    const int quad = lane >> 4, l16 = lane & 15;
    const int wr = w >> 1, wc = w & 1;

    const float* lb = lsum + b * S_LEN;
    float inv[4][4];
#pragma unroll
    for (int rt = 0; rt < 4; rt++)
#pragma unroll
        for (int r = 0; r < 4; r++)
            inv[rt][r] = 1.0f / lb[qt * 128 + wr * 64 + rt * 16 + quad * 4 + r];

    __syncthreads();
    float* Ot = (float*)smem;   // 64 x 132 (rows 16B-aligned)
#pragma unroll
    for (int h = 0; h < 2; h++) {
        if (wr == h) {
#pragma unroll
            for (int rt = 0; rt < 4; rt++)
#pragma unroll
                for (int r = 0; r < 4; r++) {
                    const int rloc = rt * 16 + quad * 4 + r;
#pragma unroll
                    for (int ct = 0; ct < 4; ct++)
                        Ot[rloc * 132 + wc * 64 + ct * 16 + l16] = acc[rt][ct][r] * inv[rt][r];
                }
        }
        __syncthreads();
        const int row = tid >> 2, qq = tid & 3;
        const float* src = Ot + row * 132 + qq * 32;
        float* dst = Out + (size_t)(b * S_LEN + qt * 128 + h * 64 + row) * DM + dt * 128 + qq * 32;
#pragma unroll
        for (int i = 0; i < 8; i++)
            *(f32x4*)(dst + i * 4) = *(const f32x4*)(src + i * 4);
        __syncthreads();
    }
}

extern "C" void kernel_launch(void* const* d_in, const int* in_sizes, int n_in,
                              void* d_out, int out_size, void* d_ws, size_t ws_size,
                              hipStream_t stream)
{
    const float* Eq = (const float*)d_in[0];
    const float* Ek = (const float*)d_in[1];
    const float* Ev = (const float*)d_in[2];
    const float* Wq = (const float*)d_in[3];
    const float* bq = (const float*)d_in[4];
    const float* Wk = (const float*)d_in[5];
    const float* bk = (const float*)d_in[6];
    const float* Wv = (const float*)d_in[7];
    const float* bv = (const float*)d_in[8];
    const int* maskp = (const int*)d_in[9];
    float* Out = (float*)d_out;

    // ws layout (~103 MB):
    //  [Qb 16M][Kb 16M][Vtb 16M][Wqb 2M][Wkb 2M][Wvb 2M][lsum 1M][P 32M | Eb overlay 48M]
    char* ws = (char*)d_ws;
    const size_t SZ_QKV = (size_t)NB * S_LEN * DM * 2;
    const size_t SZ_W   = (size_t)DM * DM * 2;
    bf16* Qb  = (bf16*)(ws);
    bf16* Kb  = (bf16*)(ws + SZ_QKV);
    bf16* Vtb = (bf16*)(ws + 2 * SZ_QKV);
    bf16* Wqb = (bf16*)(ws + 3 * SZ_QKV);
    bf16* Wkb = (bf16*)(ws + 3 * SZ_QKV + SZ_W);
    bf16* Wvb = (bf16*)(ws + 3 * SZ_QKV + 2 * SZ_W);
    float* lsum = (float*)(ws + 3 * SZ_QKV + 3 * SZ_W);
    bf16* Pbuf = (bf16*)(ws + 3 * SZ_QKV + 3 * SZ_W + (1 << 20));
    bf16* Eqb = Pbuf;   // E bf16 staging overlays P (dead once proj completes)
    bf16* Ekb = Eqb + (size_t)NB * S_LEN * DM;
    bf16* Evb = Ekb + (size_t)NB * S_LEN * DM;

    prep_kernel<<<13825, 256, 0, stream>>>(
        Wq, Wk, Wv, Eq, Ek, Ev, Wqb, Wkb, Wvb, Eqb, Ekb, Evb, lsum);

    projqk_kernel<<<1024, 256, 0, stream>>>(
        Eqb, Ekb, Wqb, Wkb, bq, bk, Qb, Kb);

    projv_qk_kernel<<<1536, 256, 0, stream>>>(
        Evb, Wvb, bv, Vtb, Qb, Kb, maskp, Pbuf, lsum);

    pv_kernel<<<512, 256, 0, stream>>>(Pbuf, Vtb, lsum, maskp, Out);
}